// Round 8
// baseline (287.825 us; speedup 1.0000x reference)
//
#include <hip/hip_runtime.h>
#include <math.h>

#define VOX (128*128*128)
#define NCH 48

typedef _Float16 half8 __attribute__((ext_vector_type(8)));
typedef float floatx4 __attribute__((ext_vector_type(4)));

__device__ __forceinline__ float waveSum(float v) {
#pragma unroll
    for (int off = 32; off > 0; off >>= 1) v += __shfl_down(v, off, 64);
    return v;
}

__device__ __forceinline__ float aload(const float* p) {
    return __hip_atomic_load(p, __ATOMIC_RELAXED, __HIP_MEMORY_SCOPE_AGENT);
}

// ws layout:
//   cnt        : int [6][4]     @ 0     (class counts per z)
//   ticket     : int            @ 2048
//   dice_stage : f32 [1024][8]  @ 4096
//   pair_stage : f32 [550][8]   @ 36864
//   Fh0/1/2 (SORTED fp16 [n][64]) @ 131072 / 1179648 / 1310720

__device__ __forceinline__ int elem_class(const int* __restrict__ target,
                                          int scale, int b, int n) {
    const int d = (scale == 0) ? 16 : (scale == 1) ? 8 : 4;
    const int s = 128 / d;
    int i3 = n % d, i2 = (n / d) % d, i1 = n / (d * d);
    return target[(size_t)b * VOX + (size_t)(i1 * s) * 16384 + (i2 * s) * 128 + (i3 * s)];
}

// ---------------- fused count + normalize + deterministic sorted scatter ----
// Each block redundantly builds the full per-z histogram (L2-resident after
// block 0) so no separate count kernel / global cursor is needed.
__global__ __launch_bounds__(256) void norm_scatter(const float* __restrict__ f0in,
                                                    const float* __restrict__ f1in,
                                                    const float* __restrict__ f2in,
                                                    const int* __restrict__ target,
                                                    _Float16* __restrict__ Fh0,
                                                    _Float16* __restrict__ Fh1,
                                                    _Float16* __restrict__ Fh2,
                                                    int* __restrict__ cnt,
                                                    int* __restrict__ ticket) {
    const int scale = blockIdx.y, b = blockIdx.z, z = scale * 2 + b, bx = blockIdx.x;
    const int N    = (scale == 0) ? 4096 : (scale == 1) ? 512 : 64;
    const int Npad = (scale == 0) ? 4096 : (scale == 1) ? 512 : 128;
    const int nCh  = (Npad + 255) / 256;
    const int tid = threadIdx.x, lane = tid & 63, w = tid >> 6;

    if (scale == 0 && b == 0 && bx == 0 && tid == 0) *ticket = 0;
    if (bx >= nCh) return;

    __shared__ int cw[16][4][4];   // [chunk][wave][class]
    int myK = -1, laneRank = 0;
    const unsigned long long below = (1ull << lane) - 1ull;

    for (int r = 0; r < nCh; r++) {
        int nn = r * 256 + tid, k = -1;
        if (nn < N)         k = elem_class(target, scale, b, nn);
        else if (nn < Npad) k = 3;
        if (r == bx) myK = k;
#pragma unroll
        for (int kk = 0; kk < 4; kk++) {
            unsigned long long mb = __ballot(k == kk);
            if (lane == 0) cw[r][w][kk] = (int)__popcll(mb);
            if (r == bx && k == kk) laneRank = (int)__popcll(mb & below);
        }
    }
    __syncthreads();

    if (bx == 0 && tid < 4) {
        int s = 0;
        for (int r = 0; r < nCh; r++)
            for (int ww = 0; ww < 4; ww++) s += cw[r][ww][tid];
        cnt[z * 4 + tid] = s;
    }
    if (myK < 0) return;

    int dest = laneRank;
    for (int k = 0; k < myK; k++) {
        int s = 0;
        for (int r = 0; r < nCh; r++)
            for (int ww = 0; ww < 4; ww++) s += cw[r][ww][k];
        dest += s;
    }
    for (int r = 0; r < bx; r++)
        for (int ww = 0; ww < 4; ww++) dest += cw[r][ww][myK];
    for (int ww = 0; ww < w; ww++) dest += cw[bx][ww][myK];

    const int n = bx * 256 + tid;
    float v[NCH];
    float inv = 0.0f;
    if (n < N) {
        const float* fi = ((scale == 0) ? f0in : (scale == 1) ? f1in : f2in)
                          + (size_t)b * NCH * N + n;
        float ss = 0.0f;
#pragma unroll
        for (int c = 0; c < NCH; c++) { v[c] = fi[(size_t)c * N]; ss += v[c] * v[c]; }
        inv = 1.0f / fmaxf(sqrtf(ss), 1e-12f);
    } else {
#pragma unroll
        for (int c = 0; c < NCH; c++) v[c] = 0.0f;
    }
    _Float16* fo = ((scale == 0) ? Fh0 : (scale == 1) ? Fh1 : Fh2)
                   + (size_t)b * Npad * 64 + (size_t)dest * 64;
#pragma unroll
    for (int g = 0; g < 8; g++) {
        half8 h;
#pragma unroll
        for (int e = 0; e < 8; e++) {
            int c = g * 8 + e;
            h[e] = (c < NCH) ? (_Float16)(v[c] * inv) : (_Float16)0.0f;
        }
        *(half8*)(fo + g * 8) = h;
    }
}

// ---------------- fused dice + MFMA pair + last-block finalize --------------
// blocks [0,550): pair; [550,1574): dice. Last finishing block (ticket) runs
// the final reduction + scalar tail and writes out[0..3].
__global__ __launch_bounds__(256) void dice_pair(const float* __restrict__ pred,
                                                 const int* __restrict__ target,
                                                 const _Float16* __restrict__ Fh0,
                                                 const _Float16* __restrict__ Fh1,
                                                 const _Float16* __restrict__ Fh2,
                                                 const int* __restrict__ cnt,
                                                 int* __restrict__ ticket,
                                                 float* __restrict__ dice_stage,
                                                 float* __restrict__ pair_stage,
                                                 const float* __restrict__ logits,
                                                 const int* __restrict__ labels,
                                                 float* __restrict__ out) {
    const int bid = blockIdx.x;
    const int tid = threadIdx.x, lane = tid & 63, w = tid >> 6;
    __shared__ float red[4][6];

    if (bid >= 550) {
        // ---------------- dice ----------------
        const int local = bid - 550;
        const int b = local >> 9, bx = local & 511;
        const float4* p0 = (const float4*)(pred + (size_t)b * 3 * VOX);
        const float4* p1 = (const float4*)(pred + (size_t)b * 3 * VOX + VOX);
        const float4* p2 = (const float4*)(pred + (size_t)b * 3 * VOX + 2 * VOX);
        const int4*   tg = (const int4*)(target + (size_t)b * VOX);

        float vals[6] = {0, 0, 0, 0, 0, 0};
        const int V4 = VOX / 4;
        for (int v = bx * 256 + tid; v < V4; v += 512 * 256) {
            float4 a = p0[v], bq = p1[v], cq = p2[v];
            int4 t = tg[v];
            float xs[4][3] = {{a.x, bq.x, cq.x}, {a.y, bq.y, cq.y},
                              {a.z, bq.z, cq.z}, {a.w, bq.w, cq.w}};
            int ts[4] = {t.x, t.y, t.z, t.w};
#pragma unroll
            for (int e = 0; e < 4; e++) {
                float e0 = __expf(xs[e][0]), e1 = __expf(xs[e][1]), e2 = __expf(xs[e][2]);
                float inv = 1.0f / (e0 + e1 + e2);
                float q1 = e1 * inv, q2 = e2 * inv;
                vals[2] += q1;
                vals[3] += q2;
                int tt = ts[e];
                vals[0] += (tt == 1) ? q1 : 0.0f;
                vals[1] += (tt == 2) ? q2 : 0.0f;
                vals[4] += (tt == 1) ? 1.0f : 0.0f;
                vals[5] += (tt == 2) ? 1.0f : 0.0f;
            }
        }
#pragma unroll
        for (int k = 0; k < 6; k++) {
            float s = waveSum(vals[k]);
            if (lane == 0) red[w][k] = s;
        }
        __syncthreads();
        if (tid < 6) {
            float s = red[0][tid] + red[1][tid] + red[2][tid] + red[3][tid];
            dice_stage[(size_t)local * 8 + tid] = s;
        }
    } else {
        // ---------------- pair ----------------
        int z, t0, nt, tstep;
        if (bid < 528)      { z = bid / 264; t0 = bid % 264; nt = 2; tstep = 264; }
        else if (bid < 548) { int i = bid - 528; z = 2 + i / 10; t0 = i % 10; nt = 1; tstep = 0; }
        else                { z = 4 + (bid - 548); t0 = 0; nt = 1; tstep = 0; }

        const int scale = z >> 1, b = z & 1;
        const int Npad = (scale == 0) ? 4096 : (scale == 1) ? 512 : 128;
        const _Float16* F = ((scale == 0) ? Fh0 : (scale == 1) ? Fh1 : Fh2)
                            + (size_t)b * Npad * 64;
        const int B1 = cnt[z * 4 + 0];
        const int B2 = B1 + cnt[z * 4 + 1];
        const int B3 = B2 + cnt[z * 4 + 2];

        const int wi = w >> 1, wj = w & 1;
        const int m = lane & 15, q = lane >> 4;

        float s[5] = {0, 0, 0, 0, 0};

        for (int it = 0; it < nt; it++) {
            int t = t0 + it * tstep;
            int by = (int)((sqrtf(8.0f * (float)t + 1.0f) - 1.0f) * 0.5f);
            while ((by + 1) * (by + 2) / 2 <= t) by++;
            while (by * (by + 1) / 2 > t) by--;
            int bx = t - by * (by + 1) / 2;

            const int ib = bx * 128 + wi * 64, jb = by * 128 + wj * 64;

            const bool diag = (ib == jb);
            const bool belowq = (ib > jb);
            int ciL = (ib >= B1) + (ib >= B2) + (ib >= B3);
            int ciH = (ib + 63 >= B1) + (ib + 63 >= B2) + (ib + 63 >= B3);
            int cjL = (jb >= B1) + (jb >= B2) + (jb >= B3);
            int cjH = (jb + 63 >= B1) + (jb + 63 >= B2) + (jb + 63 >= B3);
            const bool pure = (ciL == ciH) && (cjL == cjH) && !diag;
            int bucket = -1;
            float mult = 1.0f;
            if (pure) {
                int ci = ciL, cj = cjL;
                if (ci == 1 && cj == 1) { bucket = 0; mult = 2.0f; }
                else if (ci == 2 && cj == 2) { bucket = 1; mult = 2.0f; }
                else if (ci == 1 && cj == 2) bucket = 2;
                else if (ci == 0 && cj == 1) bucket = 3;
                else if (ci == 0 && cj == 2) bucket = 4;
            }
            if (belowq || (pure && bucket < 0)) continue;

            const _Float16* Ai = F + (size_t)(ib + m) * 64 + q * 8;
            const _Float16* Bj = F + (size_t)(jb + m) * 64 + q * 8;

            floatx4 acc_[4][4] = {};
#pragma unroll
            for (int k = 0; k < 2; k++) {
                half8 aF[4], bF[4];
#pragma unroll
                for (int t4 = 0; t4 < 4; t4++) {
                    aF[t4] = *(const half8*)(Ai + t4 * 16 * 64 + k * 32);
                    bF[t4] = *(const half8*)(Bj + t4 * 16 * 64 + k * 32);
                }
#pragma unroll
                for (int ti = 0; ti < 4; ti++)
#pragma unroll
                    for (int tj = 0; tj < 4; tj++)
                        acc_[ti][tj] = __builtin_amdgcn_mfma_f32_16x16x32_f16(
                            aF[ti], bF[tj], acc_[ti][tj], 0, 0, 0);
            }

            if (pure) {
                float ps[4] = {0, 0, 0, 0};
#pragma unroll
                for (int ti = 0; ti < 4; ti++)
#pragma unroll
                    for (int tj = 0; tj < 4; tj++)
#pragma unroll
                        for (int r = 0; r < 4; r++)
                            ps[r] += __expf(acc_[ti][tj][r] * 10.0f);
                s[bucket] += ((ps[0] + ps[1]) + (ps[2] + ps[3])) * mult;
            } else {
#pragma unroll
                for (int ti = 0; ti < 4; ti++) {
#pragma unroll
                    for (int tj = 0; tj < 4; tj++) {
#pragma unroll
                        for (int r = 0; r < 4; r++) {
                            int gi = ib + ti * 16 + q * 4 + r;
                            int gj = jb + tj * 16 + m;
                            float e = __expf(acc_[ti][tj][r] * 10.0f);
                            bool ok = !diag || (gi < gj);
                            int ci = (gi >= B1) + (gi >= B2) + (gi >= B3);
                            int cj = (gj >= B1) + (gj >= B2) + (gj >= B3);
                            s[0] += (ok && ci == 1 && cj == 1) ? e + e : 0.0f;
                            s[1] += (ok && ci == 2 && cj == 2) ? e + e : 0.0f;
                            s[2] += (ok && ci == 1 && cj == 2) ? e : 0.0f;
                            s[3] += (ok && ci == 0 && cj == 1) ? e : 0.0f;
                            s[4] += (ok && ci == 0 && cj == 2) ? e : 0.0f;
                        }
                    }
                }
            }
        }

#pragma unroll
        for (int k = 0; k < 5; k++) {
            float r = waveSum(s[k]);
            if (lane == 0) red[w][k] = r;
        }
        __syncthreads();
        if (tid < 5) {
            float r = red[0][tid] + red[1][tid] + red[2][tid] + red[3][tid];
            pair_stage[(size_t)bid * 8 + tid] = r;
        }
    }

    // -------- last-block-done finalize --------
    __threadfence();
    __shared__ int isLast;
    if (tid == 0) isLast = (atomicAdd(ticket, 1) == 1573);
    __syncthreads();
    if (!isLast) return;
    __threadfence();

    __shared__ float D[2][6], S[6][5];
    if (w < 2) {                 // dice partials, batch w
        float v[6] = {0, 0, 0, 0, 0, 0};
#pragma unroll
        for (int i = 0; i < 8; i++) {
            const float* row = dice_stage + (size_t)(w * 512 + i * 64 + lane) * 8;
#pragma unroll
            for (int k = 0; k < 6; k++) v[k] += aload(row + k);
        }
#pragma unroll
        for (int k = 0; k < 6; k++) {
            float r = waveSum(v[k]);
            if (lane == 0) D[w][k] = r;
        }
    } else {                     // pair partials: wave2 -> z=0,2,4; wave3 -> z=1,3,5
        int zz = w - 2;
        {
            float v[5] = {0, 0, 0, 0, 0};
            for (int i = lane; i < 264; i += 64) {
                const float* row = pair_stage + (size_t)(zz * 264 + i) * 8;
#pragma unroll
                for (int k = 0; k < 5; k++) v[k] += aload(row + k);
            }
#pragma unroll
            for (int k = 0; k < 5; k++) {
                float r = waveSum(v[k]);
                if (lane == 0) S[zz][k] = r;
            }
        }
        {
            float v[5] = {0, 0, 0, 0, 0};
            if (lane < 10) {
                const float* row = pair_stage + (size_t)(528 + zz * 10 + lane) * 8;
#pragma unroll
                for (int k = 0; k < 5; k++) v[k] = aload(row + k);
            }
#pragma unroll
            for (int k = 0; k < 5; k++) {
                float r = waveSum(v[k]);
                if (lane == 0) S[2 + zz][k] = r;
            }
        }
        if (lane == 0) {
            const float* row = pair_stage + (size_t)(548 + zz) * 8;
#pragma unroll
            for (int k = 0; k < 5; k++) S[4 + zz][k] = aload(row + k);
        }
    }
    __syncthreads();
    if (tid != 0) return;

    float dsum = 0.0f;
    for (int b = 0; b < 2; b++)
        for (int c = 0; c < 2; c++)
            dsum += (2.0f * D[b][c] + 1e-5f) / (D[b][2 + c] + D[b][4 + c] + 1e-5f);
    float dice = 1.0f - dsum * 0.25f;

    float fsum = 0.0f;
    for (int i = 0; i < 6; i++) {
        float x = logits[i];
        float pt = 1.0f / (1.0f + __expf(-x));
        if (labels[i] != 1) pt = 1.0f - pt;
        fsum += -0.25f * (1.0f - pt) * (1.0f - pt) * logf(pt + 1e-6f);
    }
    float focal = fsum * (1.0f / 6.0f);

    const float sw[3] = {1.0f, 0.8f, 0.6f};
    float contr = 0.0f;
    for (int sc = 0; sc < 3; sc++) {
        float bsum = 0.0f;
        for (int b = 0; b < 2; b++) {
            int z = sc * 2 + b;
            float S11 = S[z][0], S22 = S[z][1], S12 = S[z][2],
                  S01 = S[z][3], S02 = S[z][4];
            float c0 = (float)cnt[z * 4 + 0], c1 = (float)cnt[z * 4 + 1],
                  c2 = (float)cnt[z * 4 + 2];
            float l = 0.0f, c, mean;
            c = c1 * c1 - c1; mean = S11 / fmaxf(c, 1.0f);
            l += (c > 0.0f) ? -logf(mean + 1e-6f) : 0.0f;
            c = c2 * c2 - c2; mean = S22 / fmaxf(c, 1.0f);
            l += (c > 0.0f) ? -logf(mean + 1e-6f) : 0.0f;
            c = c1 * c2; mean = S12 / fmaxf(c, 1.0f);
            l += (c > 0.0f) ? log1pf(mean) : 0.0f;
            c = c0 * c1; mean = S01 / fmaxf(c, 1.0f);
            l += (c > 0.0f) ? log1pf(mean) : 0.0f;
            c = c0 * c2; mean = S02 / fmaxf(c, 1.0f);
            l += (c > 0.0f) ? log1pf(mean) : 0.0f;
            bsum += l;
        }
        contr += sw[sc] * bsum * 0.5f;
    }
    float total = dice + focal + 0.1f * contr;
    out[0] = total;
    out[1] = dice;
    out[2] = focal;
    out[3] = contr;
}

// ---------------- launch -----------------------------------------------------
extern "C" void kernel_launch(void* const* d_in, const int* in_sizes, int n_in,
                              void* d_out, int out_size, void* d_ws, size_t ws_size,
                              hipStream_t stream) {
    const float* pred   = (const float*)d_in[0];
    const int*   target = (const int*)d_in[1];
    const float* f0     = (const float*)d_in[2];
    const float* f1     = (const float*)d_in[3];
    const float* f2     = (const float*)d_in[4];
    const float* logits = (const float*)d_in[5];
    const int*   labels = (const int*)d_in[6];
    float* out = (float*)d_out;

    char* ws = (char*)d_ws;
    int*   cnt        = (int*)ws;                    // [6][4]
    int*   ticket     = (int*)(ws + 2048);
    float* dice_stage = (float*)(ws + 4096);         // [1024][8]
    float* pair_stage = (float*)(ws + 36864);        // [550][8]
    _Float16* Fh0 = (_Float16*)(ws + 131072);        // 2*4096*64
    _Float16* Fh1 = (_Float16*)(ws + 1179648);       // 2*512*64
    _Float16* Fh2 = (_Float16*)(ws + 1310720);       // 2*128*64

    norm_scatter<<<dim3(16, 3, 2), dim3(256), 0, stream>>>(f0, f1, f2, target,
                                                           Fh0, Fh1, Fh2, cnt, ticket);
    dice_pair<<<dim3(1574), dim3(256), 0, stream>>>(pred, target, Fh0, Fh1, Fh2,
                                                    cnt, ticket, dice_stage, pair_stage,
                                                    logits, labels, out);
}

// Round 9
// 135.588 us; speedup vs baseline: 2.1228x; 2.1228x over previous
//
#include <hip/hip_runtime.h>
#include <math.h>

#define VOX (128*128*128)
#define NCH 48

typedef _Float16 half8 __attribute__((ext_vector_type(8)));
typedef float floatx4 __attribute__((ext_vector_type(4)));

__device__ __forceinline__ float waveSum(float v) {
#pragma unroll
    for (int off = 32; off > 0; off >>= 1) v += __shfl_down(v, off, 64);
    return v;
}

// ws layout:
//   cnt        : int [6][4]     @ 0     (class counts per z; [3]=padding)
//   dice_stage : f32 [1024][8]  @ 4096
//   pair_stage : f32 [550][8]   @ 36864
//   Fh0/1/2 (SORTED fp16 [n][64]) @ 131072 / 1179648 / 1310720
// NOTE (R8 lesson): no device-scope fences/atomics in streaming kernels —
// cross-block reduction lives in the separate reduce_finalize kernel.

__device__ __forceinline__ int elem_class(const int* __restrict__ target,
                                          int scale, int b, int n) {
    const int d = (scale == 0) ? 16 : (scale == 1) ? 8 : 4;
    const int s = 128 / d;
    int i3 = n % d, i2 = (n / d) % d, i1 = n / (d * d);
    return target[(size_t)b * VOX + (size_t)(i1 * s) * 16384 + (i2 * s) * 128 + (i3 * s)];
}

// ---------------- fused count + normalize + deterministic sorted scatter ----
// Each block redundantly builds the full per-z histogram (target slice is
// L2-resident) -> no separate count kernel, no cursors, no atomics.
__global__ __launch_bounds__(256) void norm_scatter(const float* __restrict__ f0in,
                                                    const float* __restrict__ f1in,
                                                    const float* __restrict__ f2in,
                                                    const int* __restrict__ target,
                                                    _Float16* __restrict__ Fh0,
                                                    _Float16* __restrict__ Fh1,
                                                    _Float16* __restrict__ Fh2,
                                                    int* __restrict__ cnt) {
    const int scale = blockIdx.y, b = blockIdx.z, z = scale * 2 + b, bx = blockIdx.x;
    const int N    = (scale == 0) ? 4096 : (scale == 1) ? 512 : 64;
    const int Npad = (scale == 0) ? 4096 : (scale == 1) ? 512 : 128;
    const int nCh  = (Npad + 255) / 256;
    const int tid = threadIdx.x, lane = tid & 63, w = tid >> 6;
    if (bx >= nCh) return;

    __shared__ int cw[16][4][4];   // [chunk][wave][class]
    int myK = -1, laneRank = 0;
    const unsigned long long below = (1ull << lane) - 1ull;

    for (int r = 0; r < nCh; r++) {
        int nn = r * 256 + tid, k = -1;
        if (nn < N)         k = elem_class(target, scale, b, nn);
        else if (nn < Npad) k = 3;
        if (r == bx) myK = k;
#pragma unroll
        for (int kk = 0; kk < 4; kk++) {
            unsigned long long mb = __ballot(k == kk);
            if (lane == 0) cw[r][w][kk] = (int)__popcll(mb);
            if (r == bx && k == kk) laneRank = (int)__popcll(mb & below);
        }
    }
    __syncthreads();

    if (bx == 0 && tid < 4) {
        int s = 0;
        for (int r = 0; r < nCh; r++)
            for (int ww = 0; ww < 4; ww++) s += cw[r][ww][tid];
        cnt[z * 4 + tid] = s;
    }
    if (myK < 0) return;

    // dest = classBase + chunkPrefix + wavePrefix + laneRank
    int dest = laneRank;
    for (int k = 0; k < myK; k++) {
        int s = 0;
        for (int r = 0; r < nCh; r++)
            for (int ww = 0; ww < 4; ww++) s += cw[r][ww][k];
        dest += s;
    }
    for (int r = 0; r < bx; r++)
        for (int ww = 0; ww < 4; ww++) dest += cw[r][ww][myK];
    for (int ww = 0; ww < w; ww++) dest += cw[bx][ww][myK];

    const int n = bx * 256 + tid;
    float v[NCH];
    float inv = 0.0f;
    if (n < N) {
        const float* fi = ((scale == 0) ? f0in : (scale == 1) ? f1in : f2in)
                          + (size_t)b * NCH * N + n;
        float ss = 0.0f;
#pragma unroll
        for (int c = 0; c < NCH; c++) { v[c] = fi[(size_t)c * N]; ss += v[c] * v[c]; }
        inv = 1.0f / fmaxf(sqrtf(ss), 1e-12f);
    } else {
#pragma unroll
        for (int c = 0; c < NCH; c++) v[c] = 0.0f;
    }
    _Float16* fo = ((scale == 0) ? Fh0 : (scale == 1) ? Fh1 : Fh2)
                   + (size_t)b * Npad * 64 + (size_t)dest * 64;
#pragma unroll
    for (int g = 0; g < 8; g++) {
        half8 h;
#pragma unroll
        for (int e = 0; e < 8; e++) {
            int c = g * 8 + e;
            h[e] = (c < NCH) ? (_Float16)(v[c] * inv) : (_Float16)0.0f;
        }
        *(half8*)(fo + g * 8) = h;
    }
}

// ---------------- fused dice + MFMA pair-sum (R7 structure, no fences) ------
// blocks [0,550): pair; [550,1574): dice. Pair blocks first so they dispatch
// immediately and overlap dice's HBM wall.
__global__ __launch_bounds__(256) void dice_pair(const float* __restrict__ pred,
                                                 const int* __restrict__ target,
                                                 const _Float16* __restrict__ Fh0,
                                                 const _Float16* __restrict__ Fh1,
                                                 const _Float16* __restrict__ Fh2,
                                                 const int* __restrict__ cnt,
                                                 float* __restrict__ dice_stage,
                                                 float* __restrict__ pair_stage) {
    const int bid = blockIdx.x;
    const int tid = threadIdx.x, lane = tid & 63, w = tid >> 6;
    __shared__ float red[4][6];

    if (bid >= 550) {
        // ---------------- dice ----------------
        const int local = bid - 550;
        const int b = local >> 9, bx = local & 511;
        const float4* p0 = (const float4*)(pred + (size_t)b * 3 * VOX);
        const float4* p1 = (const float4*)(pred + (size_t)b * 3 * VOX + VOX);
        const float4* p2 = (const float4*)(pred + (size_t)b * 3 * VOX + 2 * VOX);
        const int4*   tg = (const int4*)(target + (size_t)b * VOX);

        float vals[6] = {0, 0, 0, 0, 0, 0};
        const int V4 = VOX / 4;
        for (int v = bx * 256 + tid; v < V4; v += 512 * 256) {
            float4 a = p0[v], bq = p1[v], cq = p2[v];
            int4 t = tg[v];
            float xs[4][3] = {{a.x, bq.x, cq.x}, {a.y, bq.y, cq.y},
                              {a.z, bq.z, cq.z}, {a.w, bq.w, cq.w}};
            int ts[4] = {t.x, t.y, t.z, t.w};
#pragma unroll
            for (int e = 0; e < 4; e++) {
                float e0 = __expf(xs[e][0]), e1 = __expf(xs[e][1]), e2 = __expf(xs[e][2]);
                float inv = 1.0f / (e0 + e1 + e2);
                float q1 = e1 * inv, q2 = e2 * inv;
                vals[2] += q1;
                vals[3] += q2;
                int tt = ts[e];
                vals[0] += (tt == 1) ? q1 : 0.0f;
                vals[1] += (tt == 2) ? q2 : 0.0f;
                vals[4] += (tt == 1) ? 1.0f : 0.0f;
                vals[5] += (tt == 2) ? 1.0f : 0.0f;
            }
        }
#pragma unroll
        for (int k = 0; k < 6; k++) {
            float s = waveSum(vals[k]);
            if (lane == 0) red[w][k] = s;
        }
        __syncthreads();
        if (tid < 6) {
            float s = red[0][tid] + red[1][tid] + red[2][tid] + red[3][tid];
            dice_stage[(size_t)local * 8 + tid] = s;
        }
        return;
    }

    // ---------------- pair ----------------
    int z, t0, nt, tstep;
    if (bid < 528)      { z = bid / 264; t0 = bid % 264; nt = 2; tstep = 264; }
    else if (bid < 548) { int i = bid - 528; z = 2 + i / 10; t0 = i % 10; nt = 1; tstep = 0; }
    else                { z = 4 + (bid - 548); t0 = 0; nt = 1; tstep = 0; }

    const int scale = z >> 1, b = z & 1;
    const int Npad = (scale == 0) ? 4096 : (scale == 1) ? 512 : 128;
    const _Float16* F = ((scale == 0) ? Fh0 : (scale == 1) ? Fh1 : Fh2)
                        + (size_t)b * Npad * 64;
    const int B1 = cnt[z * 4 + 0];
    const int B2 = B1 + cnt[z * 4 + 1];
    const int B3 = B2 + cnt[z * 4 + 2];

    const int wi = w >> 1, wj = w & 1;
    const int m = lane & 15, q = lane >> 4;

    float s[5] = {0, 0, 0, 0, 0};

    for (int it = 0; it < nt; it++) {
        int t = t0 + it * tstep;
        int by = (int)((sqrtf(8.0f * (float)t + 1.0f) - 1.0f) * 0.5f);
        while ((by + 1) * (by + 2) / 2 <= t) by++;
        while (by * (by + 1) / 2 > t) by--;
        int bx = t - by * (by + 1) / 2;

        const int ib = bx * 128 + wi * 64, jb = by * 128 + wj * 64;

        const bool diag = (ib == jb);
        const bool belowq = (ib > jb);
        int ciL = (ib >= B1) + (ib >= B2) + (ib >= B3);
        int ciH = (ib + 63 >= B1) + (ib + 63 >= B2) + (ib + 63 >= B3);
        int cjL = (jb >= B1) + (jb >= B2) + (jb >= B3);
        int cjH = (jb + 63 >= B1) + (jb + 63 >= B2) + (jb + 63 >= B3);
        const bool pure = (ciL == ciH) && (cjL == cjH) && !diag;
        int bucket = -1;
        float mult = 1.0f;
        if (pure) {
            int ci = ciL, cj = cjL;
            if (ci == 1 && cj == 1) { bucket = 0; mult = 2.0f; }
            else if (ci == 2 && cj == 2) { bucket = 1; mult = 2.0f; }
            else if (ci == 1 && cj == 2) bucket = 2;
            else if (ci == 0 && cj == 1) bucket = 3;
            else if (ci == 0 && cj == 2) bucket = 4;
        }
        if (belowq || (pure && bucket < 0)) continue;

        const _Float16* Ai = F + (size_t)(ib + m) * 64 + q * 8;
        const _Float16* Bj = F + (size_t)(jb + m) * 64 + q * 8;

        floatx4 acc_[4][4] = {};
#pragma unroll
        for (int k = 0; k < 2; k++) {
            half8 aF[4], bF[4];
#pragma unroll
            for (int t4 = 0; t4 < 4; t4++) {
                aF[t4] = *(const half8*)(Ai + t4 * 16 * 64 + k * 32);
                bF[t4] = *(const half8*)(Bj + t4 * 16 * 64 + k * 32);
            }
#pragma unroll
            for (int ti = 0; ti < 4; ti++)
#pragma unroll
                for (int tj = 0; tj < 4; tj++)
                    acc_[ti][tj] = __builtin_amdgcn_mfma_f32_16x16x32_f16(
                        aF[ti], bF[tj], acc_[ti][tj], 0, 0, 0);
        }

        if (pure) {
            float ps[4] = {0, 0, 0, 0};
#pragma unroll
            for (int ti = 0; ti < 4; ti++)
#pragma unroll
                for (int tj = 0; tj < 4; tj++)
#pragma unroll
                    for (int r = 0; r < 4; r++)
                        ps[r] += __expf(acc_[ti][tj][r] * 10.0f);
            s[bucket] += ((ps[0] + ps[1]) + (ps[2] + ps[3])) * mult;
        } else {
#pragma unroll
            for (int ti = 0; ti < 4; ti++) {
#pragma unroll
                for (int tj = 0; tj < 4; tj++) {
#pragma unroll
                    for (int r = 0; r < 4; r++) {
                        int gi = ib + ti * 16 + q * 4 + r;
                        int gj = jb + tj * 16 + m;
                        float e = __expf(acc_[ti][tj][r] * 10.0f);
                        bool ok = !diag || (gi < gj);
                        int ci = (gi >= B1) + (gi >= B2) + (gi >= B3);
                        int cj = (gj >= B1) + (gj >= B2) + (gj >= B3);
                        s[0] += (ok && ci == 1 && cj == 1) ? e + e : 0.0f;
                        s[1] += (ok && ci == 2 && cj == 2) ? e + e : 0.0f;
                        s[2] += (ok && ci == 1 && cj == 2) ? e : 0.0f;
                        s[3] += (ok && ci == 0 && cj == 1) ? e : 0.0f;
                        s[4] += (ok && ci == 0 && cj == 2) ? e : 0.0f;
                    }
                }
            }
        }
    }

#pragma unroll
    for (int k = 0; k < 5; k++) {
        float r = waveSum(s[k]);
        if (lane == 0) red[w][k] = r;
    }
    __syncthreads();
    if (tid < 5) {
        float r = red[0][tid] + red[1][tid] + red[2][tid] + red[3][tid];
        pair_stage[(size_t)bid * 8 + tid] = r;
    }
}

// ---------------- reduce partials + finalize (1 block, 8 waves) -------------
__global__ __launch_bounds__(512) void reduce_finalize(const float* __restrict__ dice_stage,
                                                       const int* __restrict__ cnt,
                                                       const float* __restrict__ pair_stage,
                                                       const float* __restrict__ logits,
                                                       const int* __restrict__ labels,
                                                       float* __restrict__ out) {
    __shared__ float D[2][6], S[6][5];
    const int tid = threadIdx.x, w = tid >> 6, lane = tid & 63;

    if (w < 2) {                 // dice partials, batch w
        float v[6] = {0, 0, 0, 0, 0, 0};
#pragma unroll
        for (int i = 0; i < 8; i++) {
            const float* row = dice_stage + (size_t)(w * 512 + i * 64 + lane) * 8;
#pragma unroll
            for (int k = 0; k < 6; k++) v[k] += row[k];
        }
#pragma unroll
        for (int k = 0; k < 6; k++) {
            float r = waveSum(v[k]);
            if (lane == 0) D[w][k] = r;
        }
    } else {                     // pair partials, z = w-2
        int z = w - 2;
        int start = (z == 0) ? 0 : (z == 1) ? 264 : (z == 2) ? 528
                    : (z == 3) ? 538 : (z == 4) ? 548 : 549;
        int n = (z < 2) ? 264 : (z < 4) ? 10 : 1;
        float v[5] = {0, 0, 0, 0, 0};
        for (int i = lane; i < n; i += 64) {
            const float* row = pair_stage + (size_t)(start + i) * 8;
#pragma unroll
            for (int k = 0; k < 5; k++) v[k] += row[k];
        }
#pragma unroll
        for (int k = 0; k < 5; k++) {
            float r = waveSum(v[k]);
            if (lane == 0) S[z][k] = r;
        }
    }
    __syncthreads();
    if (tid != 0) return;

    float dsum = 0.0f;
    for (int b = 0; b < 2; b++)
        for (int c = 0; c < 2; c++)
            dsum += (2.0f * D[b][c] + 1e-5f) / (D[b][2 + c] + D[b][4 + c] + 1e-5f);
    float dice = 1.0f - dsum * 0.25f;

    float fsum = 0.0f;
    for (int i = 0; i < 6; i++) {
        float x = logits[i];
        float pt = 1.0f / (1.0f + __expf(-x));
        if (labels[i] != 1) pt = 1.0f - pt;
        fsum += -0.25f * (1.0f - pt) * (1.0f - pt) * logf(pt + 1e-6f);
    }
    float focal = fsum * (1.0f / 6.0f);

    const float sw[3] = {1.0f, 0.8f, 0.6f};
    float contr = 0.0f;
    for (int sc = 0; sc < 3; sc++) {
        float bsum = 0.0f;
        for (int b = 0; b < 2; b++) {
            int z = sc * 2 + b;
            float S11 = S[z][0], S22 = S[z][1], S12 = S[z][2],
                  S01 = S[z][3], S02 = S[z][4];
            float c0 = (float)cnt[z * 4 + 0], c1 = (float)cnt[z * 4 + 1],
                  c2 = (float)cnt[z * 4 + 2];
            float l = 0.0f, c, mean;
            c = c1 * c1 - c1; mean = S11 / fmaxf(c, 1.0f);
            l += (c > 0.0f) ? -logf(mean + 1e-6f) : 0.0f;
            c = c2 * c2 - c2; mean = S22 / fmaxf(c, 1.0f);
            l += (c > 0.0f) ? -logf(mean + 1e-6f) : 0.0f;
            c = c1 * c2; mean = S12 / fmaxf(c, 1.0f);
            l += (c > 0.0f) ? log1pf(mean) : 0.0f;
            c = c0 * c1; mean = S01 / fmaxf(c, 1.0f);
            l += (c > 0.0f) ? log1pf(mean) : 0.0f;
            c = c0 * c2; mean = S02 / fmaxf(c, 1.0f);
            l += (c > 0.0f) ? log1pf(mean) : 0.0f;
            bsum += l;
        }
        contr += sw[sc] * bsum * 0.5f;
    }
    float total = dice + focal + 0.1f * contr;
    out[0] = total;
    out[1] = dice;
    out[2] = focal;
    out[3] = contr;
}

// ---------------- launch -----------------------------------------------------
extern "C" void kernel_launch(void* const* d_in, const int* in_sizes, int n_in,
                              void* d_out, int out_size, void* d_ws, size_t ws_size,
                              hipStream_t stream) {
    const float* pred   = (const float*)d_in[0];
    const int*   target = (const int*)d_in[1];
    const float* f0     = (const float*)d_in[2];
    const float* f1     = (const float*)d_in[3];
    const float* f2     = (const float*)d_in[4];
    const float* logits = (const float*)d_in[5];
    const int*   labels = (const int*)d_in[6];
    float* out = (float*)d_out;

    char* ws = (char*)d_ws;
    int*   cnt        = (int*)ws;                    // [6][4]
    float* dice_stage = (float*)(ws + 4096);         // [1024][8]
    float* pair_stage = (float*)(ws + 36864);        // [550][8]
    _Float16* Fh0 = (_Float16*)(ws + 131072);        // 2*4096*64
    _Float16* Fh1 = (_Float16*)(ws + 1179648);       // 2*512*64
    _Float16* Fh2 = (_Float16*)(ws + 1310720);       // 2*128*64

    norm_scatter<<<dim3(16, 3, 2), dim3(256), 0, stream>>>(f0, f1, f2, target,
                                                           Fh0, Fh1, Fh2, cnt);
    dice_pair<<<dim3(1574), dim3(256), 0, stream>>>(pred, target, Fh0, Fh1, Fh2,
                                                    cnt, dice_stage, pair_stage);
    reduce_finalize<<<dim3(1), dim3(512), 0, stream>>>(dice_stage, cnt, pair_stage,
                                                       logits, labels, out);
}

// Round 10
// 128.823 us; speedup vs baseline: 2.2343x; 1.0525x over previous
//
#include <hip/hip_runtime.h>
#include <math.h>

#define VOX (128*128*128)
#define NCH 48
#define SCL 3.16227766f   // sqrt(10): folds TEMP=0.1 into stored features

typedef _Float16 half8 __attribute__((ext_vector_type(8)));
typedef float floatx4 __attribute__((ext_vector_type(4)));

__device__ __forceinline__ float waveSum(float v) {
#pragma unroll
    for (int off = 32; off > 0; off >>= 1) v += __shfl_down(v, off, 64);
    return v;
}

// ws layout:
//   cnt         : int [6][4]      @ 0      (class totals per z; [3]=padding)
//   count_stage : int [6][16][4]  @ 1024   (per-block class counts)
//   dice_stage  : f32 [1024][8]   @ 4096
//   pair_stage  : f32 [550][8]    @ 36864
//   cls0/1/2    : int             @ 73728 / 106496 / 110592
//   Fh0/1/2 (SORTED fp16 [n][64], x sqrt(10)) @ 131072 / 1179648 / 1310720
// NOTE (R8 lesson): no device-scope fences/atomics in streaming kernels.
// NOTE (R6/R9 lesson): wide split kernels beat narrow/redundant fusions.

__device__ __forceinline__ int elem_class(const int* __restrict__ target,
                                          int scale, int b, int n) {
    const int d = (scale == 0) ? 16 : (scale == 1) ? 8 : 4;
    const int s = 128 / d;
    int i3 = n % d, i2 = (n / d) % d, i1 = n / (d * d);
    return target[(size_t)b * VOX + (size_t)(i1 * s) * 16384 + (i2 * s) * 128 + (i3 * s)];
}

// ---------------- per-block class counts + class array (no atomics) ---------
__global__ __launch_bounds__(256) void count_kernel(const int* __restrict__ target,
                                                    int* __restrict__ count_stage,
                                                    int* __restrict__ cls0,
                                                    int* __restrict__ cls1,
                                                    int* __restrict__ cls2) {
    const int scale = blockIdx.y, b = blockIdx.z, z = scale * 2 + b, bx = blockIdx.x;
    const int N    = (scale == 0) ? 4096 : (scale == 1) ? 512 : 64;
    const int Npad = (scale == 0) ? 4096 : (scale == 1) ? 512 : 128;
    const int n = bx * 256 + threadIdx.x;
    int myK = -1;
    if (n < N)          myK = elem_class(target, scale, b, n);
    else if (n < Npad)  myK = 3;
    if (n < Npad)
        (((scale == 0) ? cls0 : (scale == 1) ? cls1 : cls2) + b * Npad)[n] = myK;

    __shared__ int wc[4][4];
    const int lane = threadIdx.x & 63, w = threadIdx.x >> 6;
#pragma unroll
    for (int k = 0; k < 4; k++) {
        unsigned long long mb = __ballot(myK == k);
        if (lane == 0) wc[w][k] = (int)__popcll(mb);
    }
    __syncthreads();
    if (threadIdx.x < 4)   // blocks past Npad write zero rows (table stays valid)
        count_stage[(z * 16 + bx) * 4 + threadIdx.x] =
            wc[0][threadIdx.x] + wc[1][threadIdx.x] + wc[2][threadIdx.x] + wc[3][threadIdx.x];
}

// ---------------- normalize (x sqrt(10)) + deterministic sorted scatter -----
__global__ __launch_bounds__(256) void norm_scatter(const float* __restrict__ f0in,
                                                    const float* __restrict__ f1in,
                                                    const float* __restrict__ f2in,
                                                    const int* __restrict__ cls0,
                                                    const int* __restrict__ cls1,
                                                    const int* __restrict__ cls2,
                                                    _Float16* __restrict__ Fh0,
                                                    _Float16* __restrict__ Fh1,
                                                    _Float16* __restrict__ Fh2,
                                                    const int* __restrict__ count_stage,
                                                    int* __restrict__ cnt) {
    const int scale = blockIdx.y, b = blockIdx.z, z = scale * 2 + b, bx = blockIdx.x;
    const int N    = (scale == 0) ? 4096 : (scale == 1) ? 512 : 64;
    const int Npad = (scale == 0) ? 4096 : (scale == 1) ? 512 : 128;
    if (bx * 256 >= Npad) return;
    const int tid = threadIdx.x, lane = tid & 63, w = tid >> 6;
    const int n = bx * 256 + tid;

    __shared__ int cs[64];        // [16 rows][4 classes] for this z
    __shared__ int wcls[4][4];
    if (tid < 64) cs[tid] = count_stage[z * 64 + tid];

    int myK = -1;
    if (n < Npad)
        myK = (((scale == 0) ? cls0 : (scale == 1) ? cls1 : cls2) + b * Npad)[n];

    const unsigned long long below = (1ull << lane) - 1ull;
    int laneRank = 0;
#pragma unroll
    for (int k = 0; k < 4; k++) {
        unsigned long long mb = __ballot(myK == k);
        if (lane == 0) wcls[w][k] = (int)__popcll(mb);
        if (myK == k) laneRank = (int)__popcll(mb & below);
    }
    __syncthreads();

    int total[4];
#pragma unroll
    for (int k = 0; k < 4; k++) {
        int s = 0;
        for (int r = 0; r < 16; r++) s += cs[r * 4 + k];
        total[k] = s;
    }
    if (bx == 0 && tid < 4) cnt[z * 4 + tid] = total[tid];
    if (myK < 0) return;

    // dest = classBase + blockPrefix + wavePrefix + laneRank
    int dest = laneRank;
    for (int k = 0; k < myK; k++) dest += total[k];
    for (int r = 0; r < bx; r++) dest += cs[r * 4 + myK];
    for (int ww = 0; ww < w; ww++) dest += wcls[ww][myK];

    float v[NCH];
    float inv = 0.0f;
    if (n < N) {
        const float* fi = ((scale == 0) ? f0in : (scale == 1) ? f1in : f2in)
                          + (size_t)b * NCH * N + n;
        float ss = 0.0f;
#pragma unroll
        for (int c = 0; c < NCH; c++) { v[c] = fi[(size_t)c * N]; ss += v[c] * v[c]; }
        inv = SCL / fmaxf(sqrtf(ss), 1e-12f);
    } else {
#pragma unroll
        for (int c = 0; c < NCH; c++) v[c] = 0.0f;
    }
    _Float16* fo = ((scale == 0) ? Fh0 : (scale == 1) ? Fh1 : Fh2)
                   + (size_t)b * Npad * 64 + (size_t)dest * 64;
#pragma unroll
    for (int g = 0; g < 8; g++) {
        half8 h;
#pragma unroll
        for (int e = 0; e < 8; e++) {
            int c = g * 8 + e;
            h[e] = (c < NCH) ? (_Float16)(v[c] * inv) : (_Float16)0.0f;
        }
        *(half8*)(fo + g * 8) = h;
    }
}

// ---------------- fused dice + MFMA pair-sum (R7 structure) -----------------
// blocks [0,550): pair; [550,1574): dice. Pair blocks first so they dispatch
// immediately and overlap dice's HBM wall.
__global__ __launch_bounds__(256) void dice_pair(const float* __restrict__ pred,
                                                 const int* __restrict__ target,
                                                 const _Float16* __restrict__ Fh0,
                                                 const _Float16* __restrict__ Fh1,
                                                 const _Float16* __restrict__ Fh2,
                                                 const int* __restrict__ cnt,
                                                 float* __restrict__ dice_stage,
                                                 float* __restrict__ pair_stage) {
    const int bid = blockIdx.x;
    const int tid = threadIdx.x, lane = tid & 63, w = tid >> 6;
    __shared__ float red[4][6];

    if (bid >= 550) {
        // ---------------- dice ----------------
        const int local = bid - 550;
        const int b = local >> 9, bx = local & 511;
        const float4* p0 = (const float4*)(pred + (size_t)b * 3 * VOX);
        const float4* p1 = (const float4*)(pred + (size_t)b * 3 * VOX + VOX);
        const float4* p2 = (const float4*)(pred + (size_t)b * 3 * VOX + 2 * VOX);
        const int4*   tg = (const int4*)(target + (size_t)b * VOX);

        float vals[6] = {0, 0, 0, 0, 0, 0};
        const int V4 = VOX / 4;
        for (int v = bx * 256 + tid; v < V4; v += 512 * 256) {
            float4 a = p0[v], bq = p1[v], cq = p2[v];
            int4 t = tg[v];
            float xs[4][3] = {{a.x, bq.x, cq.x}, {a.y, bq.y, cq.y},
                              {a.z, bq.z, cq.z}, {a.w, bq.w, cq.w}};
            int ts[4] = {t.x, t.y, t.z, t.w};
#pragma unroll
            for (int e = 0; e < 4; e++) {
                float e0 = __expf(xs[e][0]), e1 = __expf(xs[e][1]), e2 = __expf(xs[e][2]);
                float inv = 1.0f / (e0 + e1 + e2);
                float q1 = e1 * inv, q2 = e2 * inv;
                vals[2] += q1;
                vals[3] += q2;
                int tt = ts[e];
                vals[0] += (tt == 1) ? q1 : 0.0f;
                vals[1] += (tt == 2) ? q2 : 0.0f;
                vals[4] += (tt == 1) ? 1.0f : 0.0f;
                vals[5] += (tt == 2) ? 1.0f : 0.0f;
            }
        }
#pragma unroll
        for (int k = 0; k < 6; k++) {
            float s = waveSum(vals[k]);
            if (lane == 0) red[w][k] = s;
        }
        __syncthreads();
        if (tid < 6) {
            float s = red[0][tid] + red[1][tid] + red[2][tid] + red[3][tid];
            dice_stage[(size_t)local * 8 + tid] = s;
        }
        return;
    }

    // ---------------- pair ----------------
    int z, t0, nt, tstep;
    if (bid < 528)      { z = bid / 264; t0 = bid % 264; nt = 2; tstep = 264; }
    else if (bid < 548) { int i = bid - 528; z = 2 + i / 10; t0 = i % 10; nt = 1; tstep = 0; }
    else                { z = 4 + (bid - 548); t0 = 0; nt = 1; tstep = 0; }

    const int scale = z >> 1, b = z & 1;
    const int Npad = (scale == 0) ? 4096 : (scale == 1) ? 512 : 128;
    const _Float16* F = ((scale == 0) ? Fh0 : (scale == 1) ? Fh1 : Fh2)
                        + (size_t)b * Npad * 64;
    const int B1 = cnt[z * 4 + 0];
    const int B2 = B1 + cnt[z * 4 + 1];
    const int B3 = B2 + cnt[z * 4 + 2];

    const int wi = w >> 1, wj = w & 1;
    const int m = lane & 15, q = lane >> 4;

    float s[5] = {0, 0, 0, 0, 0};

    for (int it = 0; it < nt; it++) {
        int t = t0 + it * tstep;
        int by = (int)((sqrtf(8.0f * (float)t + 1.0f) - 1.0f) * 0.5f);
        while ((by + 1) * (by + 2) / 2 <= t) by++;
        while (by * (by + 1) / 2 > t) by--;
        int bx = t - by * (by + 1) / 2;

        const int ib = bx * 128 + wi * 64, jb = by * 128 + wj * 64;

        const bool diag = (ib == jb);
        const bool belowq = (ib > jb);
        int ciL = (ib >= B1) + (ib >= B2) + (ib >= B3);
        int ciH = (ib + 63 >= B1) + (ib + 63 >= B2) + (ib + 63 >= B3);
        int cjL = (jb >= B1) + (jb >= B2) + (jb >= B3);
        int cjH = (jb + 63 >= B1) + (jb + 63 >= B2) + (jb + 63 >= B3);
        const bool pure = (ciL == ciH) && (cjL == cjH) && !diag;
        int bucket = -1;
        float mult = 1.0f;
        if (pure) {
            int ci = ciL, cj = cjL;
            if (ci == 1 && cj == 1) { bucket = 0; mult = 2.0f; }
            else if (ci == 2 && cj == 2) { bucket = 1; mult = 2.0f; }
            else if (ci == 1 && cj == 2) bucket = 2;
            else if (ci == 0 && cj == 1) bucket = 3;
            else if (ci == 0 && cj == 2) bucket = 4;
        }
        if (belowq || (pure && bucket < 0)) continue;

        const _Float16* Ai = F + (size_t)(ib + m) * 64 + q * 8;
        const _Float16* Bj = F + (size_t)(jb + m) * 64 + q * 8;

        floatx4 acc_[4][4] = {};
#pragma unroll
        for (int k = 0; k < 2; k++) {
            half8 aF[4], bF[4];
#pragma unroll
            for (int t4 = 0; t4 < 4; t4++) {
                aF[t4] = *(const half8*)(Ai + t4 * 16 * 64 + k * 32);
                bF[t4] = *(const half8*)(Bj + t4 * 16 * 64 + k * 32);
            }
#pragma unroll
            for (int ti = 0; ti < 4; ti++)
#pragma unroll
                for (int tj = 0; tj < 4; tj++)
                    acc_[ti][tj] = __builtin_amdgcn_mfma_f32_16x16x32_f16(
                        aF[ti], bF[tj], acc_[ti][tj], 0, 0, 0);
        }

        // features pre-scaled by sqrt(10): acc already holds 10*dot
        if (pure) {
            float ps[4] = {0, 0, 0, 0};
#pragma unroll
            for (int ti = 0; ti < 4; ti++)
#pragma unroll
                for (int tj = 0; tj < 4; tj++)
#pragma unroll
                    for (int r = 0; r < 4; r++)
                        ps[r] += __expf(acc_[ti][tj][r]);
            s[bucket] += ((ps[0] + ps[1]) + (ps[2] + ps[3])) * mult;
        } else {
#pragma unroll
            for (int ti = 0; ti < 4; ti++) {
#pragma unroll
                for (int tj = 0; tj < 4; tj++) {
#pragma unroll
                    for (int r = 0; r < 4; r++) {
                        int gi = ib + ti * 16 + q * 4 + r;
                        int gj = jb + tj * 16 + m;
                        float e = __expf(acc_[ti][tj][r]);
                        bool ok = !diag || (gi < gj);
                        int ci = (gi >= B1) + (gi >= B2) + (gi >= B3);
                        int cj = (gj >= B1) + (gj >= B2) + (gj >= B3);
                        s[0] += (ok && ci == 1 && cj == 1) ? e + e : 0.0f;
                        s[1] += (ok && ci == 2 && cj == 2) ? e + e : 0.0f;
                        s[2] += (ok && ci == 1 && cj == 2) ? e : 0.0f;
                        s[3] += (ok && ci == 0 && cj == 1) ? e : 0.0f;
                        s[4] += (ok && ci == 0 && cj == 2) ? e : 0.0f;
                    }
                }
            }
        }
    }

#pragma unroll
    for (int k = 0; k < 5; k++) {
        float r = waveSum(s[k]);
        if (lane == 0) red[w][k] = r;
    }
    __syncthreads();
    if (tid < 5) {
        float r = red[0][tid] + red[1][tid] + red[2][tid] + red[3][tid];
        pair_stage[(size_t)bid * 8 + tid] = r;
    }
}

// ---------------- reduce partials + finalize (1 block, 8 waves) -------------
__global__ __launch_bounds__(512) void reduce_finalize(const float* __restrict__ dice_stage,
                                                       const int* __restrict__ cnt,
                                                       const float* __restrict__ pair_stage,
                                                       const float* __restrict__ logits,
                                                       const int* __restrict__ labels,
                                                       float* __restrict__ out) {
    __shared__ float D[2][6], S[6][5];
    const int tid = threadIdx.x, w = tid >> 6, lane = tid & 63;

    if (w < 2) {                 // dice partials, batch w
        float v[6] = {0, 0, 0, 0, 0, 0};
#pragma unroll
        for (int i = 0; i < 8; i++) {
            const float* row = dice_stage + (size_t)(w * 512 + i * 64 + lane) * 8;
#pragma unroll
            for (int k = 0; k < 6; k++) v[k] += row[k];
        }
#pragma unroll
        for (int k = 0; k < 6; k++) {
            float r = waveSum(v[k]);
            if (lane == 0) D[w][k] = r;
        }
    } else {                     // pair partials, z = w-2
        int z = w - 2;
        int start = (z == 0) ? 0 : (z == 1) ? 264 : (z == 2) ? 528
                    : (z == 3) ? 538 : (z == 4) ? 548 : 549;
        int n = (z < 2) ? 264 : (z < 4) ? 10 : 1;
        float v[5] = {0, 0, 0, 0, 0};
        for (int i = lane; i < n; i += 64) {
            const float* row = pair_stage + (size_t)(start + i) * 8;
#pragma unroll
            for (int k = 0; k < 5; k++) v[k] += row[k];
        }
#pragma unroll
        for (int k = 0; k < 5; k++) {
            float r = waveSum(v[k]);
            if (lane == 0) S[z][k] = r;
        }
    }
    __syncthreads();
    if (tid != 0) return;

    float dsum = 0.0f;
    for (int b = 0; b < 2; b++)
        for (int c = 0; c < 2; c++)
            dsum += (2.0f * D[b][c] + 1e-5f) / (D[b][2 + c] + D[b][4 + c] + 1e-5f);
    float dice = 1.0f - dsum * 0.25f;

    float fsum = 0.0f;
    for (int i = 0; i < 6; i++) {
        float x = logits[i];
        float pt = 1.0f / (1.0f + __expf(-x));
        if (labels[i] != 1) pt = 1.0f - pt;
        fsum += -0.25f * (1.0f - pt) * (1.0f - pt) * logf(pt + 1e-6f);
    }
    float focal = fsum * (1.0f / 6.0f);

    const float sw[3] = {1.0f, 0.8f, 0.6f};
    float contr = 0.0f;
    for (int sc = 0; sc < 3; sc++) {
        float bsum = 0.0f;
        for (int b = 0; b < 2; b++) {
            int z = sc * 2 + b;
            float S11 = S[z][0], S22 = S[z][1], S12 = S[z][2],
                  S01 = S[z][3], S02 = S[z][4];
            float c0 = (float)cnt[z * 4 + 0], c1 = (float)cnt[z * 4 + 1],
                  c2 = (float)cnt[z * 4 + 2];
            float l = 0.0f, c, mean;
            c = c1 * c1 - c1; mean = S11 / fmaxf(c, 1.0f);
            l += (c > 0.0f) ? -logf(mean + 1e-6f) : 0.0f;
            c = c2 * c2 - c2; mean = S22 / fmaxf(c, 1.0f);
            l += (c > 0.0f) ? -logf(mean + 1e-6f) : 0.0f;
            c = c1 * c2; mean = S12 / fmaxf(c, 1.0f);
            l += (c > 0.0f) ? log1pf(mean) : 0.0f;
            c = c0 * c1; mean = S01 / fmaxf(c, 1.0f);
            l += (c > 0.0f) ? log1pf(mean) : 0.0f;
            c = c0 * c2; mean = S02 / fmaxf(c, 1.0f);
            l += (c > 0.0f) ? log1pf(mean) : 0.0f;
            bsum += l;
        }
        contr += sw[sc] * bsum * 0.5f;
    }
    float total = dice + focal + 0.1f * contr;
    out[0] = total;
    out[1] = dice;
    out[2] = focal;
    out[3] = contr;
}

// ---------------- launch -----------------------------------------------------
extern "C" void kernel_launch(void* const* d_in, const int* in_sizes, int n_in,
                              void* d_out, int out_size, void* d_ws, size_t ws_size,
                              hipStream_t stream) {
    const float* pred   = (const float*)d_in[0];
    const int*   target = (const int*)d_in[1];
    const float* f0     = (const float*)d_in[2];
    const float* f1     = (const float*)d_in[3];
    const float* f2     = (const float*)d_in[4];
    const float* logits = (const float*)d_in[5];
    const int*   labels = (const int*)d_in[6];
    float* out = (float*)d_out;

    char* ws = (char*)d_ws;
    int*   cnt         = (int*)ws;                   // [6][4]
    int*   count_stage = (int*)(ws + 1024);          // [6][16][4]
    float* dice_stage  = (float*)(ws + 4096);        // [1024][8]
    float* pair_stage  = (float*)(ws + 36864);       // [550][8]
    int*   cls0 = (int*)(ws + 73728);                // 2*4096
    int*   cls1 = (int*)(ws + 106496);               // 2*512
    int*   cls2 = (int*)(ws + 110592);               // 2*128
    _Float16* Fh0 = (_Float16*)(ws + 131072);        // 2*4096*64
    _Float16* Fh1 = (_Float16*)(ws + 1179648);       // 2*512*64
    _Float16* Fh2 = (_Float16*)(ws + 1310720);       // 2*128*64

    count_kernel<<<dim3(16, 3, 2), dim3(256), 0, stream>>>(target, count_stage,
                                                           cls0, cls1, cls2);
    norm_scatter<<<dim3(16, 3, 2), dim3(256), 0, stream>>>(f0, f1, f2,
                                                           cls0, cls1, cls2,
                                                           Fh0, Fh1, Fh2,
                                                           count_stage, cnt);
    dice_pair<<<dim3(1574), dim3(256), 0, stream>>>(pred, target, Fh0, Fh1, Fh2,
                                                    cnt, dice_stage, pair_stage);
    reduce_finalize<<<dim3(1), dim3(512), 0, stream>>>(dice_stage, cnt, pair_stage,
                                                       logits, labels, out);
}